// Round 9
// baseline (58.557 us; speedup 1.0000x reference)
//
#include <hip/hip_runtime.h>

#define WI 4096
#define HI 4096
#define WO 4090
#define HO 4090
#define SEG 36           // output rows per block
#define SLOTF 2048       // floats per ring slot (4 rows x 512)

#define VMW(n) asm volatile("s_waitcnt vmcnt(" #n ")" ::: "memory")
#define BAR()  __builtin_amdgcn_s_barrier()
#define FENCE() asm volatile("" ::: "memory")

__device__ __forceinline__ void gl_lds16(const float* g, float* l) {
    __builtin_amdgcn_global_load_lds(
        (const __attribute__((address_space(1))) void*)g,
        (__attribute__((address_space(3))) void*)l, 16, 0, 0);
}

// Stage 4-row group G: wave w loads input row gy0+4G+w (512 floats = exactly
// 2 global_load_lds per wave -> every wave's vmcnt queue is identical).
#define STAGE(G)                                                            \
  {                                                                         \
    int gy_ = gy0 + 4*(G) + w; gy_ = gy_ < HI ? gy_ : HI - 1;               \
    const float* srcr_ = x + (size_t)gy_ * WI;                              \
    float* ldb_ = ring + ((G) % 5) * SLOTF + w * 512;                       \
    gl_lds16(srcr_ + ca0, ldb_);                                            \
    gl_lds16(srcr_ + ca1, ldb_ + 256);                                      \
  }                                                                         \
  FENCE();

// One 4-row compute step; TR is a literal 0..10 -> ALL indices/guards static.
// Stores: none at TR=0, 2 at TR=1, 4 at TR=2..9, 2 at TR=10 (j=2,3 statically
// dead via oy<SEG) -> S(t) uniform across ALL blocks (no runtime y-guard).
#define STEP(TR, SB)                                                        \
  {                                                                         \
    _Pragma("unroll")                                                       \
    for (int j = 0; j < 4; ++j) {                                           \
      const float* lrow_ = ring + (SB) + j * 512 + cx2;                     \
      const float2 q0 = *(const float2*)(lrow_ + 0);                        \
      const float2 q1 = *(const float2*)(lrow_ + 2);                        \
      const float2 q2 = *(const float2*)(lrow_ + 4);                        \
      const float2 q3 = *(const float2*)(lrow_ + 6);                        \
      const float f_[8] = {q0.x,q0.y,q1.x,q1.y,q2.x,q2.y,q3.x,q3.y};        \
      _Pragma("unroll")                                                     \
      for (int ky = 0; ky < 7; ++ky) {                                      \
        if (4*(TR) + j - ky >= 0) {            /* static */                 \
          const int s_ = (4*(TR) + j - ky) & 7;                             \
          _Pragma("unroll")                                                 \
          for (int kx = 0; kx < 7; ++kx) {                                  \
            const float w_ = Wt[ky*7 + kx];                                 \
            a0[s_] += w_ * f_[kx];                                          \
            a1[s_] += w_ * f_[kx + 1];                                      \
          }                                                                 \
        }                                                                   \
      }                                                                     \
      if (4*(TR) + j - 6 >= 0 && 4*(TR) + j - 6 < SEG) { /* static */       \
        const int ss_  = (4*(TR) + j - 6) & 7;                              \
        const int gy_  = gy0 + 4*(TR) + j - 6;                              \
        if (stok) {                            /* per-lane, >=1 lane/wave */ \
          float2 o_; o_.x = a0[ss_] + bb; o_.y = a1[ss_] + bb;              \
          *(float2*)(out + (size_t)gy_ * WO + gx) = o_;                     \
        }                                                                   \
        a0[ss_] = 0.f; a1[ss_] = 0.f;                                      \
      }                                                                     \
    }                                                                       \
  }                                                                         \
  FENCE();

__global__ __launch_bounds__(256, 4) void conv7x7(
    const float* __restrict__ x, const float* __restrict__ wgt,
    const float* __restrict__ bias, float* __restrict__ out)
{
    __shared__ float ring[5 * SLOTF];      // 40,960 B -> exactly 4 blocks/CU

    const int tid  = threadIdx.x;
    const int lane = tid & 63;
    const int w    = tid >> 6;             // wave id (stages row j=w of group)
    // overlapped edge tiles: last stripe/segment recompute identical values
    // (benign double-store) so NO block-level store-guard variation exists.
    const int x0   = (blockIdx.x < 8) ? blockIdx.x * 504 : 3588;
    const int gy0  = (blockIdx.y < 113) ? blockIdx.y * SEG : (HO - SEG);

    // weights + bias: uniform addresses -> SGPR-resident
    float Wt[49];
    #pragma unroll
    for (int i = 0; i < 49; ++i) Wt[i] = wgt[i];
    const float bb = bias[0];

    // per-lane staging source cols (clamped to keep 16B loads in-row)
    int ca0 = x0 + lane * 4;        ca0 = ca0 <= 4092 ? ca0 : 4092;
    int ca1 = x0 + 256 + lane * 4;  ca1 = ca1 <= 4092 ? ca1 : 4092;

    // compute-side: 2 cols/thread; pairs past 252 belong to the next stripe
    // (read a safe clamped window, never store)
    const int cx2  = (2 * tid <= 504) ? 2 * tid : 504;
    const int gx   = x0 + 2 * tid;
    const bool stok = (2 * tid <= 504) && (gx + 1 < WO);

    float a0[8], a1[8];
    #pragma unroll
    for (int s = 0; s < 8; ++s) { a0[s] = 0.f; a1[s] = 0.f; }

    // prologue: 3 groups in flight
    STAGE(0) STAGE(1) STAGE(2)

    // Exact in-order vmcnt counts (loads+stores) s.t. stage-t is retired at
    // iter t while stages t+1..t+3 AND all stores stay in flight:
    //   N(t) = S(t-3) + 2 + S(t-2) + 2 + S(t-1),  S = {0,2,4,4,4,4,4,4,4,4,2}
    VMW(4);  BAR(); FENCE(); STAGE(3)  STEP(0, 0)
    VMW(4);  BAR(); FENCE(); STAGE(4)  STEP(1, SLOTF)
    VMW(6);  BAR(); FENCE(); STAGE(5)  STEP(2, 2*SLOTF)
    VMW(10); BAR(); FENCE(); STAGE(6)  STEP(3, 3*SLOTF)
    VMW(14); BAR(); FENCE(); STAGE(7)  STEP(4, 4*SLOTF)
    VMW(16); BAR(); FENCE(); STAGE(8)  STEP(5, 0)
    VMW(16); BAR(); FENCE(); STAGE(9)  STEP(6, SLOTF)
    VMW(16); BAR(); FENCE(); STAGE(10) STEP(7, 2*SLOTF)
    VMW(16); BAR(); FENCE();           STEP(8, 3*SLOTF)
    VMW(14); BAR(); FENCE();           STEP(9, 4*SLOTF)
    VMW(12); BAR(); FENCE();           STEP(10, 0)
}

extern "C" void kernel_launch(void* const* d_in, const int* in_sizes, int n_in,
                              void* d_out, int out_size, void* d_ws, size_t ws_size,
                              hipStream_t stream) {
    const float* x = (const float*)d_in[0];
    const float* w = (const float*)d_in[1];
    const float* b = (const float*)d_in[2];
    float* out = (float*)d_out;
    // 9 stripes (last overlapped) x 114 segments (last overlapped)
    dim3 grid(9, 114);
    conv7x7<<<grid, 256, 0, stream>>>(x, w, b, out);
}

// Round 10
// 41.635 us; speedup vs baseline: 1.4064x; 1.4064x over previous
//
#include <hip/hip_runtime.h>

#define WI 4096
#define HI 4096
#define WO 4090
#define HO 4090
#define TH 24            // output rows per block
#define IH 30            // staged input rows
#define IWP 520          // floats per LDS row (518 needed, 16B multiple)
#define CPR 130          // 16-byte chunks per LDS row
#define ACH (18*CPR)     // phase-A chunks (input rows 0..17)  = 2340
#define NCH (IH*CPR)     // total chunks                       = 3900

__device__ __forceinline__ void gl_lds16(const float* g, float* l) {
    __builtin_amdgcn_global_load_lds(
        (const __attribute__((address_space(1))) void*)g,
        (__attribute__((address_space(3))) void*)l, 16, 0, 0);
}

__global__ __launch_bounds__(512, 4) void conv7x7(
    const float* __restrict__ x, const float* __restrict__ wgt,
    const float* __restrict__ bias, float* __restrict__ out)
{
    __shared__ float lds[IH * IWP];   // 62,400 B -> 2 blocks/CU (16 waves)

    const int tid = threadIdx.x;
    const int x0  = blockIdx.x * 512;
    const int y0  = blockIdx.y * TH;

    // weights + bias: uniform addresses -> SGPR-resident scalar loads
    float Wt[49];
    #pragma unroll
    for (int i = 0; i < 49; ++i) Wt[i] = wgt[i];
    const float bb = bias[0];

    const int gx  = x0 + tid;
    const bool xok = gx < WO;

    // stage chunks [c0, c0+n): chunk c = LDS floats [4c, 4c+4), source row
    // c/130, col 4*(c%130). Per wave-instruction the LDS dest is uniform
    // base + lane*16 (linear) as required; global src is per-lane (clamped:
    // clamped values only ever feed guarded-off outputs).
    auto stage = [&](int c0, int n) {
        for (int c = c0 + tid; c < c0 + n; c += 512) {
            const int rr = c / CPR;            // magic-mul div
            const int c4 = c - rr * CPR;
            int gy = y0 + rr;       gy  = gy  < HI ? gy : HI - 1;
            int gxs = x0 + c4 * 4;  gxs = gxs <= WI - 4 ? gxs : WI - 4;
            gl_lds16(x + (size_t)gy * WI + gxs, lds + c * 4);
        }
    };

    float acc[7];
    #pragma unroll
    for (int s = 0; s < 7; ++s) acc[s] = 0.f;

    // one fully-static row step (r is a compile-time constant after unroll)
    #define DOROW(r)                                                        \
    {                                                                       \
        float f[7];                                                         \
        _Pragma("unroll")                                                   \
        for (int k = 0; k < 7; ++k) f[k] = lds[(r) * IWP + tid + k];        \
        _Pragma("unroll")                                                   \
        for (int ky = 0; ky < 7; ++ky) {                                    \
            const int oy = (r) - ky;               /* static */             \
            if (oy >= 0 && oy < TH) {                                       \
                const int s = oy % 7;              /* static */             \
                _Pragma("unroll")                                           \
                for (int kx = 0; kx < 7; ++kx)                              \
                    acc[s] += Wt[ky * 7 + kx] * f[kx];                      \
            }                                                               \
        }                                                                   \
        if ((r) >= 6) {                            /* static */             \
            const int oy = (r) - 6;                                         \
            const int s  = oy % 7;                 /* static */             \
            const int gy = y0 + oy;                                         \
            if (xok && gy < HO)                                             \
                out[(size_t)gy * WO + gx] = acc[s] + bb;                    \
            acc[s] = 0.f;                                                   \
        }                                                                   \
    }

    // ---- phase A: stage input rows 0..17; exposed drain once per block ----
    stage(0, ACH);
    __syncthreads();

    // ---- issue phase-B stage (rows 18..29), fire-and-forget ----
    stage(ACH, NCH - ACH);

    // ---- compute A: input rows 0..17 (covers stage-B's HBM latency) ----
    #pragma unroll
    for (int r = 0; r < 18; ++r) DOROW(r)

    __syncthreads();   // vmcnt(0) drain of stage-B: issued ~2600 cyc ago -> free

    // ---- compute B: input rows 18..29 ----
    #pragma unroll
    for (int r = 18; r < 30; ++r) DOROW(r)

    #undef DOROW
}

extern "C" void kernel_launch(void* const* d_in, const int* in_sizes, int n_in,
                              void* d_out, int out_size, void* d_ws, size_t ws_size,
                              hipStream_t stream) {
    const float* x = (const float*)d_in[0];
    const float* w = (const float*)d_in[1];
    const float* b = (const float*)d_in[2];
    float* out = (float*)d_out;
    // x: 8 stripes x 512 cols (stripe 7 outputs masked past 4089)
    // y: ceil(4090/24) = 171 segments
    dim3 grid(8, 171);
    conv7x7<<<grid, 512, 0, stream>>>(x, w, b, out);
}

// Round 11
// 36.680 us; speedup vs baseline: 1.5964x; 1.1351x over previous
//
#include <hip/hip_runtime.h>

#define WI 4096
#define HI 4096
#define WO 4090
#define HO 4090
#define TH 12            // output rows per block
#define IH 18            // staged input rows
#define IWP 520          // floats per LDS row (518 needed, 16B multiple)
#define CPR 130          // 16-byte chunks per LDS row
#define ACH (12*CPR)     // phase-A chunks (input rows 0..11) = 1560
#define NCH (IH*CPR)     // total chunks                      = 2340

__device__ __forceinline__ void gl_lds16(const float* g, float* l) {
    __builtin_amdgcn_global_load_lds(
        (const __attribute__((address_space(1))) void*)g,
        (__attribute__((address_space(3))) void*)l, 16, 0, 0);
}

__global__ __launch_bounds__(256, 4) void conv7x7(
    const float* __restrict__ x, const float* __restrict__ wgt,
    const float* __restrict__ bias, float* __restrict__ out)
{
    __shared__ float lds[IH * IWP];   // 37,440 B -> 4 blocks/CU (16 waves)

    const int tid = threadIdx.x;
    const int x0  = blockIdx.x * 512;
    const int y0  = blockIdx.y * TH;

    // weights + bias: uniform addresses -> SGPR-resident scalar loads
    float Wt[49];
    #pragma unroll
    for (int i = 0; i < 49; ++i) Wt[i] = wgt[i];
    const float bb = bias[0];

    const int cx  = 2 * tid;          // local first output col
    const int gx  = x0 + cx;          // global first output col
    const bool stok = (gx + 1 < WO);  // per-lane store mask (pair store)

    // stage chunks [c0, c0+n): chunk c -> LDS floats [4c,4c+4), src row c/130,
    // col 4*(c%130). LDS dest per wave-instr = uniform base + lane*16 (linear,
    // as required); global src per-lane, clamped (clamped data only feeds
    // masked-off outputs).
    auto stage = [&](int c0, int n) {
        for (int c = c0 + tid; c < c0 + n; c += 256) {
            const int rr = c / CPR;            // magic-mul div
            const int c4 = c - rr * CPR;
            int gy = y0 + rr;       gy  = gy  < HI ? gy : HI - 1;
            int gxs = x0 + c4 * 4;  gxs = gxs <= WI - 4 ? gxs : WI - 4;
            gl_lds16(x + (size_t)gy * WI + gxs, lds + c * 4);
        }
    };

    float a0[7], a1[7];
    #pragma unroll
    for (int s = 0; s < 7; ++s) { a0[s] = 0.f; a1[s] = 0.f; }

    // one fully-static row step (r compile-time): 4x ds_read_b64 + 98 FMA
    #define DOROW(r)                                                        \
    {                                                                       \
        const float* lrow_ = lds + (r) * IWP + cx;                          \
        const float2 q0 = *(const float2*)(lrow_ + 0);                      \
        const float2 q1 = *(const float2*)(lrow_ + 2);                      \
        const float2 q2 = *(const float2*)(lrow_ + 4);                      \
        const float2 q3 = *(const float2*)(lrow_ + 6);                      \
        const float f_[8] = {q0.x,q0.y,q1.x,q1.y,q2.x,q2.y,q3.x,q3.y};      \
        _Pragma("unroll")                                                   \
        for (int ky = 0; ky < 7; ++ky) {                                    \
            const int oy = (r) - ky;               /* static */             \
            if (oy >= 0 && oy < TH) {                                       \
                const int s = oy % 7;              /* static */             \
                _Pragma("unroll")                                           \
                for (int kx = 0; kx < 7; ++kx) {                            \
                    const float w_ = Wt[ky * 7 + kx];                       \
                    a0[s] += w_ * f_[kx];                                   \
                    a1[s] += w_ * f_[kx + 1];                               \
                }                                                           \
            }                                                               \
        }                                                                   \
        if ((r) >= 6) {                            /* static */             \
            const int oy = (r) - 6;                                         \
            const int s  = oy % 7;                 /* static */             \
            const int gy = y0 + oy;                                         \
            if (stok && gy < HO) {                                          \
                float2 o_; o_.x = a0[s] + bb; o_.y = a1[s] + bb;            \
                *(float2*)(out + (size_t)gy * WO + gx) = o_;                \
            }                                                               \
            a0[s] = 0.f; a1[s] = 0.f;                                       \
        }                                                                   \
    }

    // ---- phase A: stage input rows 0..11; exposed drain once per block ----
    stage(0, ACH);
    __syncthreads();

    // ---- issue phase-B stage (rows 12..17), fire-and-forget ----
    stage(ACH, NCH - ACH);

    // ---- compute A: rows 0..11 (~2900 cyc, covers stage-B HBM latency) ----
    #pragma unroll
    for (int r = 0; r < 12; ++r) DOROW(r)

    __syncthreads();   // vmcnt(0) drain of stage-B: aged a full phase -> ~free

    // ---- compute B: rows 12..17 ----
    #pragma unroll
    for (int r = 12; r < 18; ++r) DOROW(r)

    #undef DOROW
}

extern "C" void kernel_launch(void* const* d_in, const int* in_sizes, int n_in,
                              void* d_out, int out_size, void* d_ws, size_t ws_size,
                              hipStream_t stream) {
    const float* x = (const float*)d_in[0];
    const float* w = (const float*)d_in[1];
    const float* b = (const float*)d_in[2];
    float* out = (float*)d_out;
    // x: 8 stripes x 512 cols (last stripe masks cols >= 4090)
    // y: ceil(4090/12) = 341 segments
    dim3 grid(8, 341);
    conv7x7<<<grid, 256, 0, stream>>>(x, w, b, out);
}